// Round 1
// baseline (222.163 us; speedup 1.0000x reference)
//
#include <hip/hip_runtime.h>
#include <hip/hip_bf16.h>

constexpr int Bn = 8, Hn = 512, Ln = 4096, N2n = 32;

typedef __attribute__((ext_vector_type(8))) short bf16x8;
typedef __attribute__((ext_vector_type(4))) float f32x4;

typedef void __attribute__((address_space(1))) gvoid;
typedef void __attribute__((address_space(3))) lvoid;

__device__ __forceinline__ unsigned short f2bf(float f) {
  unsigned int u = __float_as_uint(f);
  u += 0x7fffu + ((u >> 16) & 1u);   // RNE
  return (unsigned short)(u >> 16);
}

// ---------------- K0: per-(h,n) recurrence params ----------------
__global__ void prep_params(const float* __restrict__ C, const float* __restrict__ log_dt,
                            const float* __restrict__ log_A_real, const float* __restrict__ A_imag,
                            float4* __restrict__ params) {
  int idx = blockIdx.x * 256 + threadIdx.x;
  if (idx >= Hn * N2n) return;
  int h = idx / N2n;
  float dt = expf(log_dt[h]);
  float Ar = -expf(log_A_real[idx]);
  float Ai = A_imag[idx];
  float dr = Ar * dt, di = Ai * dt;
  float er = expf(dr);
  float wr = er * cosf(di), wi = er * sinf(di);
  float e1r = wr - 1.0f, e1i = wi;                 // exp(dtA) - 1
  float den = Ar * Ar + Ai * Ai;
  float tr = (e1r * Ar + e1i * Ai) / den;          // (exp(dtA)-1)/A
  float ti = (e1i * Ar - e1r * Ai) / den;
  float Cr = C[idx * 2 + 0], Ci = C[idx * 2 + 1];
  float c2r = 2.0f * (Cr * tr - Ci * ti);
  float c2i = 2.0f * (Cr * ti + Ci * tr);
  params[idx] = make_float4(wr, wi, c2r, -c2i);    // store -C2i for fma form
}

// ---------------- K1: W fp32 -> bf16 ----------------
__global__ void conv_w(const float* __restrict__ W, unsigned short* __restrict__ Wb) {
  int i = blockIdx.x * 256 + threadIdx.x;
  if (i < 2 * Hn * Hn) Wb[i] = f2bf(W[i]);
}

// ---------------- K2: SSM scan + skip + GELU, writes gyT[b][l][h] bf16 ----------------
// block = 256 thr = 4 waves; each wave: 2 sequences (lane halves), lane&31 = state n.
// 8 sequences/block share b, h = h0..h0+7.
__global__ __launch_bounds__(256, 2) void s4d_scan(
    const float* __restrict__ u, const float4* __restrict__ params,
    const float* __restrict__ Dv, unsigned short* __restrict__ gyT) {
  __shared__ float cbuf[4][2][32][33];     // [wave][seq][t][n]+pad
  __shared__ float utile[4][2][32];
  __shared__ unsigned short tbuf[2][32][8];  // [dbuf][l][h-in-block]

  const int tid = threadIdx.x;
  const int w = tid >> 6, lane = tid & 63;
  const int seq = lane >> 5, n = lane & 31;
  const int g = w * 2 + seq;                // 0..7
  const int s0 = blockIdx.x * 8;            // global sequence base
  const int b = s0 / Hn, h0 = s0 % Hn;      // 8 divides 512: no b crossing
  const int h = h0 + g;

  const float4 p = params[h * N2n + n];
  const float wr = p.x, wi = p.y, c2r = p.z, c2in = p.w;
  const float Dh = Dv[h];
  const float* __restrict__ up = u + (size_t)(s0 + g) * Ln;

  float* __restrict__ ub  = &utile[w][seq][0];
  float* __restrict__ cwp = &cbuf[w][seq][0][n];   // write: +t*33
  float* __restrict__ crp = &cbuf[w][seq][n][0];   // read row t=n: +j

  float sr = 0.0f, si = 0.0f;

  for (int tile = 0; tile < Ln / 32; ++tile) {
    const int l0 = tile * 32;
    const float ustage = up[l0 + n];   // coalesced 128B per half-wave
    ub[n] = ustage;
    asm volatile("s_waitcnt lgkmcnt(0)" ::: "memory");
#pragma unroll
    for (int t = 0; t < 32; ++t) {
      float uv = ub[t];                                // broadcast read
      float nsr = fmaf(wr, sr, fmaf(-wi, si, uv));     // Re(w*s)+u
      float nsi = fmaf(wi, sr, wr * si);               // Im(w*s)
      sr = nsr; si = nsi;
      cwp[t * 33] = fmaf(c2r, sr, c2in * si);          // Re(C2*s)
    }
    asm volatile("s_waitcnt lgkmcnt(0)" ::: "memory");
    // deferred reduction: lane handles (seq, t=n)
    float acc = 0.0f;
#pragma unroll
    for (int j = 0; j < 32; ++j) acc += crp[j];
    float v = fmaf(ustage, Dh, acc);                   // skip connection
    float ge = 0.5f * v * (1.0f + erff(v * 0.70710678118654752f));  // exact GELU
    tbuf[tile & 1][n][g] = f2bf(ge);
    __syncthreads();
    if (tid < 32) {   // 16B chunk per l-row: gyT[b][l0+tid][h0..h0+7]
      uint4 val = *reinterpret_cast<const uint4*>(&tbuf[tile & 1][tid][0]);
      *reinterpret_cast<uint4*>(&gyT[((size_t)b * Ln + l0 + tid) * Hn + h0]) = val;
    }
  }
}

// ---------------- K3: dual GEMM (a,g) + bias + GLU ----------------
// out[b][h][l] = (W[h,:]·gy + b[h]) * sigmoid(W[512+h,:]·gy + b[512+h])
// A = W row-major (k-contig), B = gyT[b][l][k] (k-contig). 128x128 tile, BK=64.
__global__ __launch_bounds__(256, 2) void s4d_gemm(
    const unsigned short* __restrict__ Wb, const unsigned short* __restrict__ gyT,
    const float* __restrict__ bias, float* __restrict__ out) {
  __shared__ unsigned short As[2][128][64];  // [a/g][m-row][k]
  __shared__ unsigned short Bs[128][64];     // [l-row][k]

  const int tid = threadIdx.x;
  const int wid = tid >> 6, lane = tid & 63;
  const int ntg = blockIdx.x & 255;          // 256 N-tiles (b, l0)
  const int mt = blockIdx.x >> 8;            // 4 M-tiles
  const int b = ntg >> 5;
  const int l0 = (ntg & 31) * 128;
  const int m0 = mt * 128;
  const int wm = wid >> 1, wn = wid & 1;

  f32x4 acc[2][4][4];
#pragma unroll
  for (int a = 0; a < 2; ++a)
#pragma unroll
    for (int i = 0; i < 4; ++i)
#pragma unroll
      for (int j = 0; j < 4; ++j) acc[a][i][j] = (f32x4){0.f, 0.f, 0.f, 0.f};

  const int srow = lane >> 3;          // 0..7 rows per 1KB chunk
  const int sk = (lane & 7) * 8;       // 8 bf16 = 16B per lane

  for (int kt = 0; kt < 8; ++kt) {
    const int k0 = kt * 64;
#pragma unroll
    for (int q = 0; q < 4; ++q) {
      const int r8 = wid * 32 + q * 8;
      const unsigned short* srcA = Wb + ((size_t)(m0 + r8 + srow) * 512 + k0 + sk);
      __builtin_amdgcn_global_load_lds((const gvoid*)srcA, (lvoid*)&As[0][r8][0], 16, 0, 0);
      const unsigned short* srcG = Wb + ((size_t)(Hn + m0 + r8 + srow) * 512 + k0 + sk);
      __builtin_amdgcn_global_load_lds((const gvoid*)srcG, (lvoid*)&As[1][r8][0], 16, 0, 0);
      const unsigned short* srcB = gyT + (((size_t)b * Ln + l0 + r8 + srow) * Hn + k0 + sk);
      __builtin_amdgcn_global_load_lds((const gvoid*)srcB, (lvoid*)&Bs[r8][0], 16, 0, 0);
    }
    asm volatile("s_waitcnt vmcnt(0)" ::: "memory");
    __syncthreads();
#pragma unroll
    for (int kk = 0; kk < 2; ++kk) {
      const int koff = kk * 32 + (lane >> 4) * 8;
      bf16x8 af0[4], af1[4], bfv[4];
#pragma unroll
      for (int mf = 0; mf < 4; ++mf) {
        af0[mf] = *(const bf16x8*)&As[0][wm * 64 + mf * 16 + (lane & 15)][koff];
        af1[mf] = *(const bf16x8*)&As[1][wm * 64 + mf * 16 + (lane & 15)][koff];
      }
#pragma unroll
      for (int nf = 0; nf < 4; ++nf)
        bfv[nf] = *(const bf16x8*)&Bs[wn * 64 + nf * 16 + (lane & 15)][koff];
#pragma unroll
      for (int mf = 0; mf < 4; ++mf)
#pragma unroll
        for (int nf = 0; nf < 4; ++nf) {
          acc[0][mf][nf] = __builtin_amdgcn_mfma_f32_16x16x32_bf16(af0[mf], bfv[nf], acc[0][mf][nf], 0, 0, 0);
          acc[1][mf][nf] = __builtin_amdgcn_mfma_f32_16x16x32_bf16(af1[mf], bfv[nf], acc[1][mf][nf], 0, 0, 0);
        }
    }
    __syncthreads();
  }

  // epilogue: C/D layout col=lane&15, row=(lane>>4)*4+r
  const int col = lane & 15, r0 = (lane >> 4) * 4;
#pragma unroll
  for (int mf = 0; mf < 4; ++mf) {
    const int hbase = m0 + wm * 64 + mf * 16 + r0;
#pragma unroll
    for (int nf = 0; nf < 4; ++nf) {
      const int l = l0 + wn * 64 + nf * 16 + col;
      f32x4 va = acc[0][mf][nf], vg = acc[1][mf][nf];
#pragma unroll
      for (int r = 0; r < 4; ++r) {
        const int hh = hbase + r;
        float av = va[r] + bias[hh];
        float gv = vg[r] + bias[Hn + hh];
        out[((size_t)b * Hn + hh) * Ln + l] = av / (1.0f + expf(-gv));
      }
    }
  }
}

extern "C" void kernel_launch(void* const* d_in, const int* in_sizes, int n_in,
                              void* d_out, int out_size, void* d_ws, size_t ws_size,
                              hipStream_t stream) {
  (void)in_sizes; (void)n_in; (void)out_size; (void)ws_size;
  const float* u     = (const float*)d_in[0];
  const float* C     = (const float*)d_in[1];
  const float* logdt = (const float*)d_in[2];
  const float* logA  = (const float*)d_in[3];
  const float* Aim   = (const float*)d_in[4];
  const float* Dv    = (const float*)d_in[5];
  const float* W     = (const float*)d_in[6];
  const float* bias  = (const float*)d_in[7];
  float* out = (float*)d_out;

  char* ws = (char*)d_ws;
  float4* params      = (float4*)ws;                                  // 256 KB
  unsigned short* Wb  = (unsigned short*)(ws + (256 << 10));          // 1 MB
  unsigned short* gyT = (unsigned short*)(ws + (256 << 10) + (1 << 20)); // 32 MB

  hipLaunchKernelGGL(prep_params, dim3(64), dim3(256), 0, stream, C, logdt, logA, Aim, params);
  hipLaunchKernelGGL(conv_w, dim3(2048), dim3(256), 0, stream, W, Wb);
  hipLaunchKernelGGL(s4d_scan, dim3(Bn * Hn / 8), dim3(256), 0, stream, u, params, Dv, gyT);
  hipLaunchKernelGGL(s4d_gemm, dim3(4 * 256), dim3(256), 0, stream, Wb, gyT, bias, out);
}